// Round 8
// baseline (1410.189 us; speedup 1.0000x reference)
//
#include <hip/hip_runtime.h>
#include <hip/hip_bf16.h>

#define N_ATOMS   200000
#define D_IN      256
#define D_OUT     256
#define N_SPECIES 4
#define N_STRUCT  2000
#define M_PAD     2048
#define KFLAT     1024
#define SEG_D     16

// diagnostic repeat factors (base dur = measured / REP)
#define REP_WT    64
#define REP_SEG   8
#define REP_GEMM  64

typedef __attribute__((ext_vector_type(8))) short bf16x8;
typedef __attribute__((ext_vector_type(4))) float f32x4;

typedef const __attribute__((address_space(1))) float gfloat;
typedef __attribute__((address_space(3))) float lfloat;

__device__ inline unsigned short f2bf(float f) {
    unsigned int u = __float_as_uint(f);
    unsigned int r = (u + 0x7fffu + ((u >> 16) & 1u)) >> 16;   // RNE
    return (unsigned short)r;
}

// ---- ws layout (bytes) ----
// 0        : Wt  bf16 [16][256][64]   = 524288
// 524288   : S   bf16 [2048][1024]    = 4194304
// 4718592  : cnt f32  [2048][4]       = 32768

// K1 (diag x64): write-coalesced W transpose/convert
__global__ void k_wt2(const float* __restrict__ W, unsigned short* __restrict__ Wt) {
    int gid = blockIdx.x * 256 + threadIdx.x;
    int o   = gid * 4;
    int kbg = o >> 14;
    int nn  = (o >> 6) & 255;
    int kp  = o & 63;
    int s   = kbg >> 2, kb = kbg & 3;
    int k0  = kb * 64 + kp;
    const float* wb = W + (size_t)s * 65536 + (size_t)k0 * 256 + nn;
    for (int p = 0; p < REP_WT; ++p) {
        asm volatile("" ::: "memory");     // force genuine reloads each pass
        ushort4 u;
        u.x = f2bf(wb[0]);
        u.y = f2bf(wb[256]);
        u.z = f2bf(wb[512]);
        u.w = f2bf(wb[768]);
        if (p == REP_WT - 1) *(ushort4*)(Wt + o) = u;
        else asm volatile("" :: "v"(u.x), "v"(u.y), "v"(u.z), "v"(u.w));
    }
}

// 64-ary lower_bound over sorted sidx
__device__ __forceinline__ int lb64(const int* __restrict__ sidx, int key, int lane) {
    int lo = 0, hi = N_ATOMS;
    while (hi - lo > 64) {
        int step = (hi - lo + 63) >> 6;
        int pos  = lo + lane * step;
        int v    = (pos < hi) ? sidx[pos] : 0x7fffffff;
        unsigned long long m = __ballot(v < key);
        int c = __popcll(m);
        int nlo = (c == 0)  ? lo : (lo + (c - 1) * step + 1);
        int nhi = (c == 64) ? hi : min(hi, lo + c * step);
        lo = nlo; hi = nhi;
    }
    int pos = lo + lane;
    int v   = (pos < hi) ? sidx[pos] : 0x7fffffff;
    unsigned long long m = __ballot(v < key);
    return lo + __popcll(m);
}

// K2 (diag x8): one wave = one structure; spec masks pre-balloted into SGPRs
// BEFORE the pipeline, so the hot loop's vmem queue holds ONLY ring loads.
__global__ __launch_bounds__(256) void k_seg5(
        const float* __restrict__ x, const int* __restrict__ spec,
        const int* __restrict__ sidx, unsigned short* __restrict__ S,
        float* __restrict__ cnt) {

    __shared__ __align__(16) float ring[4][SEG_D][256];   // 64 KB

    int t = threadIdx.x, w = t >> 6, lane = t & 63;
    int g = blockIdx.x * 4 + w;
    if (g >= N_STRUCT) return;

    int s0 = lb64(sidx, g,     lane);
    int s1 = lb64(sidx, g + 1, lane);
    int n  = s1 - s0;

    f32x4 a0 = (f32x4){0.f,0.f,0.f,0.f}, a1 = a0, a2 = a0, a3 = a0;
    float c0 = 0.f, c1 = 0.f, c2 = 0.f, c3 = 0.f;

    if (n > 0) {
        int nm1 = n - 1;
        const float* gp0 = x + (size_t)s0 * 256 + lane * 4;

        unsigned long long m0[4], m1[4];
        bool fits = (n <= 256);
        if (fits) {
#pragma unroll
            for (int c = 0; c < 4; ++c) {
                int sv = spec[s0 + min(c * 64 + lane, nm1)];
                m0[c] = __ballot((sv & 1) != 0);
                m1[c] = __ballot((sv & 2) != 0);
            }
        }

        for (int pass = 0; pass < REP_SEG; ++pass) {
            f32x4 t0 = (f32x4){0.f,0.f,0.f,0.f}, t1 = t0, t2 = t0, t3 = t0;
            float d0 = 0.f, d1 = 0.f, d2 = 0.f, d3 = 0.f;

            asm volatile("s_waitcnt vmcnt(0)" ::: "memory");  // clean queue per pass
#pragma unroll
            for (int j = 0; j < 15; ++j) {
                int rr = min(j, nm1);
                __builtin_amdgcn_global_load_lds(
                    (gfloat*)(gp0 + (size_t)rr * 256),
                    (lfloat*)&ring[w][j][0], 16, 0, 0);
            }

#define CONS4(vv, sp)                                                     \
            switch (sp) {                                                 \
                case 0: t0 += vv; d0 += 1.f; break;                       \
                case 1: t1 += vv; d1 += 1.f; break;                       \
                case 2: t2 += vv; d2 += 1.f; break;                       \
                default: t3 += vv; d3 += 1.f; break; }

            if (fits) {
#pragma unroll
                for (int c = 0; c < 4; ++c) {
                    int cb = c * 64;
                    if (cb < n) {
                        unsigned long long mm0 = m0[c], mm1 = m1[c];
                        int ce = min(n, cb + 64);
                        for (int j = cb; j < ce; ++j) {
                            asm volatile("s_waitcnt vmcnt(14)" ::: "memory");
                            f32x4 v = *(const f32x4*)&ring[w][j & (SEG_D - 1)][lane * 4];
                            int r  = j - cb;
                            int sp = (int)((mm0 >> r) & 1ull) | ((int)((mm1 >> r) & 1ull) << 1);
                            CONS4(v, sp);
                            int rr = min(j + 15, nm1);
                            __builtin_amdgcn_global_load_lds(
                                (gfloat*)(gp0 + (size_t)rr * 256),
                                (lfloat*)&ring[w][(j + 15) & (SEG_D - 1)][0], 16, 0, 0);
                        }
                    }
                }
            } else {
                for (int cb = 0; cb < n; cb += 64) {
                    int spv = spec[s0 + min(cb + lane, nm1)];
                    asm volatile("s_waitcnt vmcnt(0)" ::: "memory");
                    unsigned long long mm0 = __ballot((spv & 1) != 0);
                    unsigned long long mm1 = __ballot((spv & 2) != 0);
                    int ce = min(n, cb + 64);
                    for (int j = cb; j < ce; ++j) {
                        f32x4 v = *(const f32x4*)&ring[w][j & (SEG_D - 1)][lane * 4];
                        int r  = j - cb;
                        int sp = (int)((mm0 >> r) & 1ull) | ((int)((mm1 >> r) & 1ull) << 1);
                        CONS4(v, sp);
                        int rr = min(j + 15, nm1);
                        __builtin_amdgcn_global_load_lds(
                            (gfloat*)(gp0 + (size_t)rr * 256),
                            (lfloat*)&ring[w][(j + 15) & (SEG_D - 1)][0], 16, 0, 0);
                        asm volatile("s_waitcnt vmcnt(14)" ::: "memory");
                    }
                }
            }
#undef CONS4

            if (pass == REP_SEG - 1) {
                a0 = t0; a1 = t1; a2 = t2; a3 = t3;
                c0 = d0; c1 = d1; c2 = d2; c3 = d3;
            } else {
                asm volatile("" ::
                    "v"(t0[0]), "v"(t0[1]), "v"(t0[2]), "v"(t0[3]),
                    "v"(t1[0]), "v"(t1[1]), "v"(t1[2]), "v"(t1[3]),
                    "v"(t2[0]), "v"(t2[1]), "v"(t2[2]), "v"(t2[3]),
                    "v"(t3[0]), "v"(t3[1]), "v"(t3[2]), "v"(t3[3]),
                    "v"(d0), "v"(d1), "v"(d2), "v"(d3));
            }
        }
    }

    unsigned short* Sg = S + (size_t)g * KFLAT + lane * 4;
    ushort4 u;
    u.x = f2bf(a0[0]); u.y = f2bf(a0[1]); u.z = f2bf(a0[2]); u.w = f2bf(a0[3]);
    *(ushort4*)(Sg + 0)   = u;
    u.x = f2bf(a1[0]); u.y = f2bf(a1[1]); u.z = f2bf(a1[2]); u.w = f2bf(a1[3]);
    *(ushort4*)(Sg + 256) = u;
    u.x = f2bf(a2[0]); u.y = f2bf(a2[1]); u.z = f2bf(a2[2]); u.w = f2bf(a2[3]);
    *(ushort4*)(Sg + 512) = u;
    u.x = f2bf(a3[0]); u.y = f2bf(a3[1]); u.z = f2bf(a3[2]); u.w = f2bf(a3[3]);
    *(ushort4*)(Sg + 768) = u;

    if (lane == 0) {
        float4 c4; c4.x = c0; c4.y = c1; c4.z = c2; c4.w = c3;
        *(float4*)(cnt + (size_t)g * 4) = c4;
    }
}

// K3 (diag x64): barrier-free GEMM, frags direct from L2
__global__ __launch_bounds__(256) void k_gemm3(
        const unsigned short* __restrict__ S, const float* __restrict__ cnt,
        const float* __restrict__ b, const unsigned short* __restrict__ Wt,
        float* __restrict__ out) {

    int t = threadIdx.x, nt = t >> 6, lane = t & 63;
    int l15 = lane & 15, l4 = lane >> 4;
    int g0 = blockIdx.x * 16;

    f32x4 acc[4];
#pragma unroll
    for (int n = 0; n < 4; ++n) acc[n] = (f32x4){0.f, 0.f, 0.f, 0.f};

    const unsigned short* arow = S + (size_t)(g0 + l15) * KFLAT + l4 * 8;

    for (int pass = 0; pass < REP_GEMM; ++pass) {
        f32x4 tac[4];
#pragma unroll
        for (int n = 0; n < 4; ++n) tac[n] = (f32x4){0.f, 0.f, 0.f, 0.f};
        asm volatile("" ::: "memory");     // force genuine reloads each pass

#pragma unroll 4
        for (int kbg = 0; kbg < 16; ++kbg) {
            const unsigned short* wkb = Wt + (size_t)kbg * 16384 + l4 * 8;
#pragma unroll
            for (int ks = 0; ks < 2; ++ks) {
                bf16x8 af = *(const bf16x8*)(arow + kbg * 64 + ks * 32);
#pragma unroll
                for (int n = 0; n < 4; ++n) {
                    bf16x8 bfr = *(const bf16x8*)(wkb + (size_t)(nt * 64 + n * 16 + l15) * 64 + ks * 32);
                    tac[n] = __builtin_amdgcn_mfma_f32_16x16x32_bf16(af, bfr, tac[n], 0, 0, 0);
                }
            }
        }

        if (pass == REP_GEMM - 1) {
#pragma unroll
            for (int n = 0; n < 4; ++n) acc[n] = tac[n];
        } else {
            asm volatile("" ::
                "v"(tac[0][0]), "v"(tac[0][1]), "v"(tac[0][2]), "v"(tac[0][3]),
                "v"(tac[1][0]), "v"(tac[1][1]), "v"(tac[1][2]), "v"(tac[1][3]),
                "v"(tac[2][0]), "v"(tac[2][1]), "v"(tac[2][2]), "v"(tac[2][3]),
                "v"(tac[3][0]), "v"(tac[3][1]), "v"(tac[3][2]), "v"(tac[3][3]));
        }
    }

    float bv[4][4];
#pragma unroll
    for (int n = 0; n < 4; ++n) {
        int col = nt * 64 + n * 16 + l15;
#pragma unroll
        for (int s = 0; s < 4; ++s) bv[n][s] = b[s * 256 + col];
    }

#pragma unroll
    for (int r = 0; r < 4; ++r) {
        int grow = g0 + l4 * 4 + r;
        if (grow < N_STRUCT) {
            float4 c4 = *(const float4*)(cnt + (size_t)grow * 4);
#pragma unroll
            for (int n = 0; n < 4; ++n) {
                int col = nt * 64 + n * 16 + l15;
                out[(size_t)grow * 256 + col] =
                    acc[n][r] + c4.x * bv[n][0] + c4.y * bv[n][1]
                              + c4.z * bv[n][2] + c4.w * bv[n][3];
            }
        }
    }
}

extern "C" void kernel_launch(void* const* d_in, const int* in_sizes, int n_in,
                              void* d_out, int out_size, void* d_ws, size_t ws_size,
                              hipStream_t stream) {
    const float* x    = (const float*)d_in[0];
    const float* W    = (const float*)d_in[1];
    const float* b    = (const float*)d_in[2];
    const int* spec   = (const int*)d_in[3];
    const int* sidx   = (const int*)d_in[4];
    float* out        = (float*)d_out;

    char* ws = (char*)d_ws;
    unsigned short* Wt = (unsigned short*)ws;               // 524288 B
    unsigned short* S  = (unsigned short*)(ws + 524288);    // 4194304 B
    float* cnt  = (float*)(ws + 4718592);                   // 32768 B

    k_wt2  <<<512, 256, 0, stream>>>(W, Wt);
    k_seg5 <<<(N_STRUCT + 3) / 4, 256, 0, stream>>>(x, spec, sidx, S, cnt);
    k_gemm3<<<M_PAD / 16, 256, 0, stream>>>(S, cnt, b, Wt, out);
}

// Round 9
// 59.840 us; speedup vs baseline: 23.5659x; 23.5659x over previous
//
#include <hip/hip_runtime.h>
#include <hip/hip_bf16.h>

#define N_ATOMS   200000
#define D_IN      256
#define D_OUT     256
#define N_SPECIES 4
#define N_STRUCT  2000
#define M_PAD     2048
#define KFLAT     1024
#define SEG_D     16

typedef __attribute__((ext_vector_type(8))) short bf16x8;
typedef __attribute__((ext_vector_type(4))) float f32x4;

typedef const __attribute__((address_space(1))) float gfloat;
typedef __attribute__((address_space(3))) float lfloat;

__device__ inline unsigned short f2bf(float f) {
    unsigned int u = __float_as_uint(f);
    unsigned int r = (u + 0x7fffu + ((u >> 16) & 1u)) >> 16;   // RNE
    return (unsigned short)r;
}

// ---- ws layout (bytes) ----
// 0        : Wt  bf16 [16][256][64]   = 524288   (kbg = s*4 + (k>>6), [n][k'] per block)
// 524288   : S   bf16 [2048][1024]    = 4194304  (rows >= 2000 stay poison, never stored)
// 4718592  : cnt f32  [2048][4]       = 32768

// K1: write-coalesced W transpose/convert (~1 us)
__global__ void k_wt2(const float* __restrict__ W, unsigned short* __restrict__ Wt) {
    int gid = blockIdx.x * 256 + threadIdx.x;
    int o   = gid * 4;
    int kbg = o >> 14;
    int nn  = (o >> 6) & 255;
    int kp  = o & 63;
    int s   = kbg >> 2, kb = kbg & 3;
    int k0  = kb * 64 + kp;
    const float* wb = W + (size_t)s * 65536 + (size_t)k0 * 256 + nn;
    ushort4 u;
    u.x = f2bf(wb[0]);
    u.y = f2bf(wb[256]);
    u.z = f2bf(wb[512]);
    u.w = f2bf(wb[768]);
    *(ushort4*)(Wt + o) = u;
}

// 64-ary lower_bound over sorted sidx (whole wave participates)
__device__ __forceinline__ int lb64(const int* __restrict__ sidx, int key, int lane) {
    int lo = 0, hi = N_ATOMS;
    while (hi - lo > 64) {
        int step = (hi - lo + 63) >> 6;
        int pos  = lo + lane * step;
        int v    = (pos < hi) ? sidx[pos] : 0x7fffffff;
        unsigned long long m = __ballot(v < key);
        int c = __popcll(m);
        int nlo = (c == 0)  ? lo : (lo + (c - 1) * step + 1);
        int nhi = (c == 64) ? hi : min(hi, lo + c * step);
        lo = nlo; hi = nhi;
    }
    int pos = lo + lane;
    int v   = (pos < hi) ? sidx[pos] : 0x7fffffff;
    unsigned long long m = __ballot(v < key);
    return lo + __popcll(m);
}

// K2: ONE WAVE = ONE STRUCTURE (near HBM floor per R8 diagnostic).
// Spec masks pre-balloted into SGPRs BEFORE the ring primes, so the hot
// loop's vmem queue holds ONLY ring loads -> exact vmcnt(14) bookkeeping.
__global__ __launch_bounds__(256) void k_seg6(
        const float* __restrict__ x, const int* __restrict__ spec,
        const int* __restrict__ sidx, unsigned short* __restrict__ S,
        float* __restrict__ cnt) {

    __shared__ __align__(16) float ring[4][SEG_D][256];   // 64 KB

    int t = threadIdx.x, w = t >> 6, lane = t & 63;
    int g = blockIdx.x * 4 + w;
    if (g >= N_STRUCT) return;

    int s0 = lb64(sidx, g,     lane);
    int s1 = lb64(sidx, g + 1, lane);
    int n  = s1 - s0;

    f32x4 a0 = (f32x4){0.f,0.f,0.f,0.f}, a1 = a0, a2 = a0, a3 = a0;
    float c0 = 0.f, c1 = 0.f, c2 = 0.f, c3 = 0.f;

    if (n > 0) {
        int nm1 = n - 1;
        const float* gp0 = x + (size_t)s0 * 256 + lane * 4;

        unsigned long long m0[4], m1[4];
        bool fits = (n <= 256);
        if (fits) {
#pragma unroll
            for (int c = 0; c < 4; ++c) {
                int sv = spec[s0 + min(c * 64 + lane, nm1)];
                m0[c] = __ballot((sv & 1) != 0);
                m1[c] = __ballot((sv & 2) != 0);
            }
        }

        // drain lb64 + spec vector loads so vmcnt counts only ring loads
        asm volatile("s_waitcnt vmcnt(0)" ::: "memory");

#pragma unroll
        for (int j = 0; j < 15; ++j) {
            int rr = min(j, nm1);
            __builtin_amdgcn_global_load_lds(
                (gfloat*)(gp0 + (size_t)rr * 256),
                (lfloat*)&ring[w][j][0], 16, 0, 0);
        }

#define CONS4(vv, sp)                                                     \
        switch (sp) {                                                     \
            case 0: a0 += vv; c0 += 1.f; break;                           \
            case 1: a1 += vv; c1 += 1.f; break;                           \
            case 2: a2 += vv; c2 += 1.f; break;                           \
            default: a3 += vv; c3 += 1.f; break; }

        if (fits) {
#pragma unroll
            for (int c = 0; c < 4; ++c) {
                int cb = c * 64;
                if (cb < n) {
                    unsigned long long mm0 = m0[c], mm1 = m1[c];
                    int ce = min(n, cb + 64);
                    for (int j = cb; j < ce; ++j) {
                        asm volatile("s_waitcnt vmcnt(14)" ::: "memory");
                        f32x4 v = *(const f32x4*)&ring[w][j & (SEG_D - 1)][lane * 4];
                        int r  = j - cb;
                        int sp = (int)((mm0 >> r) & 1ull) | ((int)((mm1 >> r) & 1ull) << 1);
                        CONS4(v, sp);
                        int rr = min(j + 15, nm1);
                        __builtin_amdgcn_global_load_lds(
                            (gfloat*)(gp0 + (size_t)rr * 256),
                            (lfloat*)&ring[w][(j + 15) & (SEG_D - 1)][0], 16, 0, 0);
                    }
                }
            }
        } else {
            // rare tail path (n > 256): chunked spec reload with full drain
            for (int cb = 0; cb < n; cb += 64) {
                int spv = spec[s0 + min(cb + lane, nm1)];
                asm volatile("s_waitcnt vmcnt(0)" ::: "memory");
                unsigned long long mm0 = __ballot((spv & 1) != 0);
                unsigned long long mm1 = __ballot((spv & 2) != 0);
                int ce = min(n, cb + 64);
                for (int j = cb; j < ce; ++j) {
                    f32x4 v = *(const f32x4*)&ring[w][j & (SEG_D - 1)][lane * 4];
                    int r  = j - cb;
                    int sp = (int)((mm0 >> r) & 1ull) | ((int)((mm1 >> r) & 1ull) << 1);
                    CONS4(v, sp);
                    int rr = min(j + 15, nm1);
                    __builtin_amdgcn_global_load_lds(
                        (gfloat*)(gp0 + (size_t)rr * 256),
                        (lfloat*)&ring[w][(j + 15) & (SEG_D - 1)][0], 16, 0, 0);
                    asm volatile("s_waitcnt vmcnt(14)" ::: "memory");
                }
            }
        }
#undef CONS4
    }

    unsigned short* Sg = S + (size_t)g * KFLAT + lane * 4;
    ushort4 u;
    u.x = f2bf(a0[0]); u.y = f2bf(a0[1]); u.z = f2bf(a0[2]); u.w = f2bf(a0[3]);
    *(ushort4*)(Sg + 0)   = u;
    u.x = f2bf(a1[0]); u.y = f2bf(a1[1]); u.z = f2bf(a1[2]); u.w = f2bf(a1[3]);
    *(ushort4*)(Sg + 256) = u;
    u.x = f2bf(a2[0]); u.y = f2bf(a2[1]); u.z = f2bf(a2[2]); u.w = f2bf(a2[3]);
    *(ushort4*)(Sg + 512) = u;
    u.x = f2bf(a3[0]); u.y = f2bf(a3[1]); u.z = f2bf(a3[2]); u.w = f2bf(a3[3]);
    *(ushort4*)(Sg + 768) = u;

    if (lane == 0) {
        float4 c4; c4.x = c0; c4.y = c1; c4.z = c2; c4.w = c3;
        *(float4*)(cnt + (size_t)g * 4) = c4;
    }
}

// K3: K-split GEMM. 512 blocks x 4 waves (8 waves/CU). Block owns a 16x64
// output tile; wave w computes the K-slice of species w (K=256), then a
// flat contiguous LDS reduce combines the 4 partials; wave 0 does the
// bias+cnt epilogue and the store. Per-wave chain: 40 loads, 32 MFMAs.
__global__ __launch_bounds__(256) void k_gemm4(
        const unsigned short* __restrict__ S, const float* __restrict__ cnt,
        const float* __restrict__ b, const unsigned short* __restrict__ Wt,
        float* __restrict__ out) {

    __shared__ __align__(16) f32x4 red[3 * 4 * 64];   // [w-1][n][lane], 12 KB

    int t = threadIdx.x, w = t >> 6, lane = t & 63;
    int l15 = lane & 15, l4 = lane >> 4;
    int bid = blockIdx.x;
    int g0 = (bid >> 2) * 16;
    int c0 = (bid & 3) * 64;

    f32x4 acc[4];
#pragma unroll
    for (int n = 0; n < 4; ++n) acc[n] = (f32x4){0.f, 0.f, 0.f, 0.f};

    const unsigned short* arow = S + (size_t)(g0 + l15) * KFLAT + w * 256 + l4 * 8;
    const unsigned short* wsp  = Wt + (size_t)w * 4 * 16384 + l4 * 8;

#pragma unroll
    for (int kb = 0; kb < 4; ++kb) {
#pragma unroll
        for (int ks = 0; ks < 2; ++ks) {
            bf16x8 af = *(const bf16x8*)(arow + kb * 64 + ks * 32);
#pragma unroll
            for (int n = 0; n < 4; ++n) {
                bf16x8 bfr = *(const bf16x8*)(wsp + (size_t)kb * 16384
                                + (size_t)(c0 + n * 16 + l15) * 64 + ks * 32);
                acc[n] = __builtin_amdgcn_mfma_f32_16x16x32_bf16(af, bfr, acc[n], 0, 0, 0);
            }
        }
    }

    if (w > 0) {
#pragma unroll
        for (int n = 0; n < 4; ++n) red[(w - 1) * 256 + n * 64 + lane] = acc[n];
    }
    __syncthreads();
    if (w == 0) {
#pragma unroll
        for (int n = 0; n < 4; ++n)
            acc[n] += red[0 * 256 + n * 64 + lane]
                    + red[1 * 256 + n * 64 + lane]
                    + red[2 * 256 + n * 64 + lane];

        float bv[4][4];
#pragma unroll
        for (int n = 0; n < 4; ++n) {
            int col = c0 + n * 16 + l15;
#pragma unroll
            for (int s = 0; s < 4; ++s) bv[n][s] = b[s * 256 + col];
        }

#pragma unroll
        for (int r = 0; r < 4; ++r) {
            int grow = g0 + l4 * 4 + r;
            if (grow < N_STRUCT) {
                float4 c4 = *(const float4*)(cnt + (size_t)grow * 4);
#pragma unroll
                for (int n = 0; n < 4; ++n) {
                    int col = c0 + n * 16 + l15;
                    out[(size_t)grow * 256 + col] =
                        acc[n][r] + c4.x * bv[n][0] + c4.y * bv[n][1]
                                  + c4.z * bv[n][2] + c4.w * bv[n][3];
                }
            }
        }
    }
}

extern "C" void kernel_launch(void* const* d_in, const int* in_sizes, int n_in,
                              void* d_out, int out_size, void* d_ws, size_t ws_size,
                              hipStream_t stream) {
    const float* x    = (const float*)d_in[0];
    const float* W    = (const float*)d_in[1];
    const float* b    = (const float*)d_in[2];
    const int* spec   = (const int*)d_in[3];
    const int* sidx   = (const int*)d_in[4];
    float* out        = (float*)d_out;

    char* ws = (char*)d_ws;
    unsigned short* Wt = (unsigned short*)ws;               // 524288 B
    unsigned short* S  = (unsigned short*)(ws + 524288);    // 4194304 B
    float* cnt  = (float*)(ws + 4718592);                   // 32768 B

    k_wt2  <<<512, 256, 0, stream>>>(W, Wt);
    k_seg6 <<<(N_STRUCT + 3) / 4, 256, 0, stream>>>(x, spec, sidx, S, cnt);
    k_gemm4<<<(M_PAD / 16) * (D_OUT / 64), 256, 0, stream>>>(S, cnt, b, Wt, out);
}

// Round 10
// 54.398 us; speedup vs baseline: 25.9238x; 1.1001x over previous
//
#include <hip/hip_runtime.h>
#include <hip/hip_bf16.h>

#define N_ATOMS   200000
#define D_IN      256
#define D_OUT     256
#define N_SPECIES 4
#define N_STRUCT  2000
#define M_PAD     2048
#define KFLAT     1024
#define SEG_D     16
#define WT_BLOCKS 512

typedef __attribute__((ext_vector_type(8))) short bf16x8;
typedef __attribute__((ext_vector_type(4))) float f32x4;

typedef const __attribute__((address_space(1))) float gfloat;
typedef __attribute__((address_space(3))) float lfloat;

__device__ inline unsigned short f2bf(float f) {
    unsigned int u = __float_as_uint(f);
    unsigned int r = (u + 0x7fffu + ((u >> 16) & 1u)) >> 16;   // RNE
    return (unsigned short)r;
}

// ---- ws layout (bytes) ----
// 0        : Wt  bf16 [16][256][64]   = 524288   (kbg = s*4 + (k>>6), [n][k'] per block)
// 524288   : S   bf16 [2048][1024]    = 4194304  (rows >= 2000 stay poison, never stored)
// 4718592  : cnt f32  [2048][4]       = 32768

// 64-ary lower_bound over sorted sidx (whole wave participates)
__device__ __forceinline__ int lb64(const int* __restrict__ sidx, int key, int lane) {
    int lo = 0, hi = N_ATOMS;
    while (hi - lo > 64) {
        int step = (hi - lo + 63) >> 6;
        int pos  = lo + lane * step;
        int v    = (pos < hi) ? sidx[pos] : 0x7fffffff;
        unsigned long long m = __ballot(v < key);
        int c = __popcll(m);
        int nlo = (c == 0)  ? lo : (lo + (c - 1) * step + 1);
        int nhi = (c == 64) ? hi : min(hi, lo + c * step);
        lo = nlo; hi = nhi;
    }
    int pos = lo + lane;
    int v   = (pos < hi) ? sidx[pos] : 0x7fffffff;
    unsigned long long m = __ballot(v < key);
    return lo + __popcll(m);
}

// K1 (fused): blocks [0,512) = write-coalesced W transpose; [512,1012) = seg.
// Seg: one wave = one structure, depth-15 global_load_lds ring, counted
// vmcnt(14); spec masks pre-balloted into SGPRs so the hot loop's vmem queue
// holds ONLY ring loads.
__global__ __launch_bounds__(256) void k_fused(
        const float* __restrict__ x, const float* __restrict__ W,
        const int* __restrict__ spec, const int* __restrict__ sidx,
        unsigned short* __restrict__ Wt, unsigned short* __restrict__ S,
        float* __restrict__ cnt) {

    __shared__ __align__(16) float ring[4][SEG_D][256];   // 64 KB

    int t = threadIdx.x;
    int bid = blockIdx.x;

    if (bid < WT_BLOCKS) {
        int gid = bid * 256 + t;
        int o   = gid * 4;
        int kbg = o >> 14;
        int nn  = (o >> 6) & 255;
        int kp  = o & 63;
        int s   = kbg >> 2, kb = kbg & 3;
        int k0  = kb * 64 + kp;
        const float* wb = W + (size_t)s * 65536 + (size_t)k0 * 256 + nn;
        ushort4 u;
        u.x = f2bf(wb[0]);
        u.y = f2bf(wb[256]);
        u.z = f2bf(wb[512]);
        u.w = f2bf(wb[768]);
        *(ushort4*)(Wt + o) = u;
        return;
    }

    int w = t >> 6, lane = t & 63;
    int g = (bid - WT_BLOCKS) * 4 + w;
    if (g >= N_STRUCT) return;

    int s0 = lb64(sidx, g,     lane);
    int s1 = lb64(sidx, g + 1, lane);
    int n  = s1 - s0;

    f32x4 a0 = (f32x4){0.f,0.f,0.f,0.f}, a1 = a0, a2 = a0, a3 = a0;
    float c0 = 0.f, c1 = 0.f, c2 = 0.f, c3 = 0.f;

    if (n > 0) {
        int nm1 = n - 1;
        const float* gp0 = x + (size_t)s0 * 256 + lane * 4;

        unsigned long long m0[4], m1[4];
        bool fits = (n <= 256);
        if (fits) {
#pragma unroll
            for (int c = 0; c < 4; ++c) {
                int sv = spec[s0 + min(c * 64 + lane, nm1)];
                m0[c] = __ballot((sv & 1) != 0);
                m1[c] = __ballot((sv & 2) != 0);
            }
        }

        // drain lb64 + spec vector loads so vmcnt counts only ring loads
        asm volatile("s_waitcnt vmcnt(0)" ::: "memory");

#pragma unroll
        for (int j = 0; j < 15; ++j) {
            int rr = min(j, nm1);
            __builtin_amdgcn_global_load_lds(
                (gfloat*)(gp0 + (size_t)rr * 256),
                (lfloat*)&ring[w][j][0], 16, 0, 0);
        }

#define CONS4(vv, sp)                                                     \
        switch (sp) {                                                     \
            case 0: a0 += vv; c0 += 1.f; break;                           \
            case 1: a1 += vv; c1 += 1.f; break;                           \
            case 2: a2 += vv; c2 += 1.f; break;                           \
            default: a3 += vv; c3 += 1.f; break; }

        if (fits) {
#pragma unroll
            for (int c = 0; c < 4; ++c) {
                int cb = c * 64;
                if (cb < n) {
                    unsigned long long mm0 = m0[c], mm1 = m1[c];
                    int ce = min(n, cb + 64);
                    for (int j = cb; j < ce; ++j) {
                        asm volatile("s_waitcnt vmcnt(14)" ::: "memory");
                        f32x4 v = *(const f32x4*)&ring[w][j & (SEG_D - 1)][lane * 4];
                        int r  = j - cb;
                        int sp = (int)((mm0 >> r) & 1ull) | ((int)((mm1 >> r) & 1ull) << 1);
                        CONS4(v, sp);
                        int rr = min(j + 15, nm1);
                        __builtin_amdgcn_global_load_lds(
                            (gfloat*)(gp0 + (size_t)rr * 256),
                            (lfloat*)&ring[w][(j + 15) & (SEG_D - 1)][0], 16, 0, 0);
                    }
                }
            }
        } else {
            for (int cb = 0; cb < n; cb += 64) {
                int spv = spec[s0 + min(cb + lane, nm1)];
                asm volatile("s_waitcnt vmcnt(0)" ::: "memory");
                unsigned long long mm0 = __ballot((spv & 1) != 0);
                unsigned long long mm1 = __ballot((spv & 2) != 0);
                int ce = min(n, cb + 64);
                for (int j = cb; j < ce; ++j) {
                    f32x4 v = *(const f32x4*)&ring[w][j & (SEG_D - 1)][lane * 4];
                    int r  = j - cb;
                    int sp = (int)((mm0 >> r) & 1ull) | ((int)((mm1 >> r) & 1ull) << 1);
                    CONS4(v, sp);
                    int rr = min(j + 15, nm1);
                    __builtin_amdgcn_global_load_lds(
                        (gfloat*)(gp0 + (size_t)rr * 256),
                        (lfloat*)&ring[w][(j + 15) & (SEG_D - 1)][0], 16, 0, 0);
                    asm volatile("s_waitcnt vmcnt(14)" ::: "memory");
                }
            }
        }
#undef CONS4
    }

    unsigned short* Sg = S + (size_t)g * KFLAT + lane * 4;
    ushort4 u;
    u.x = f2bf(a0[0]); u.y = f2bf(a0[1]); u.z = f2bf(a0[2]); u.w = f2bf(a0[3]);
    *(ushort4*)(Sg + 0)   = u;
    u.x = f2bf(a1[0]); u.y = f2bf(a1[1]); u.z = f2bf(a1[2]); u.w = f2bf(a1[3]);
    *(ushort4*)(Sg + 256) = u;
    u.x = f2bf(a2[0]); u.y = f2bf(a2[1]); u.z = f2bf(a2[2]); u.w = f2bf(a2[3]);
    *(ushort4*)(Sg + 512) = u;
    u.x = f2bf(a3[0]); u.y = f2bf(a3[1]); u.z = f2bf(a3[2]); u.w = f2bf(a3[3]);
    *(ushort4*)(Sg + 768) = u;

    if (lane == 0) {
        float4 c4; c4.x = c0; c4.y = c1; c4.z = c2; c4.w = c3;
        *(float4*)(cnt + (size_t)g * 4) = c4;
    }
}

// K2: K-split GEMM, M=32 rows x 32 cols per block (512 blocks, 8 waves/CU).
// Wave w computes species-w K-slice for the whole 32x32 tile; all 4 waves
// participate in the LDS reduce (wave w finalizes combo m=w>>1, n=w&1).
// L2 traffic: Wt 32 MB + S 32 MB (vs 262+16 in R9's gemm4).
__global__ __launch_bounds__(256) void k_gemm5(
        const unsigned short* __restrict__ S, const float* __restrict__ cnt,
        const float* __restrict__ b, const unsigned short* __restrict__ Wt,
        float* __restrict__ out) {

    __shared__ __align__(16) f32x4 red[4][2][2][64];   // [w][m][n][lane] = 16 KB

    int t = threadIdx.x, w = t >> 6, lane = t & 63;
    int l15 = lane & 15, l4 = lane >> 4;
    int bid = blockIdx.x;
    int g0 = (bid >> 3) * 32;        // 64 row-groups
    int c0 = (bid & 7) * 32;         // 8 col-blocks

    f32x4 acc[2][2];
#pragma unroll
    for (int m = 0; m < 2; ++m)
#pragma unroll
        for (int n = 0; n < 2; ++n) acc[m][n] = (f32x4){0.f, 0.f, 0.f, 0.f};

    const unsigned short* arow = S + (size_t)(g0 + l15) * KFLAT + w * 256 + l4 * 8;
    const unsigned short* wsp  = Wt + (size_t)w * 4 * 16384 + l4 * 8;

#pragma unroll
    for (int kb = 0; kb < 4; ++kb) {
#pragma unroll
        for (int ks = 0; ks < 2; ++ks) {
            bf16x8 af[2];
#pragma unroll
            for (int m = 0; m < 2; ++m)
                af[m] = *(const bf16x8*)(arow + (size_t)m * 16 * KFLAT + kb * 64 + ks * 32);
#pragma unroll
            for (int n = 0; n < 2; ++n) {
                bf16x8 bfr = *(const bf16x8*)(wsp + (size_t)kb * 16384
                                + (size_t)(c0 + n * 16 + l15) * 64 + ks * 32);
#pragma unroll
                for (int m = 0; m < 2; ++m)
                    acc[m][n] = __builtin_amdgcn_mfma_f32_16x16x32_bf16(af[m], bfr, acc[m][n], 0, 0, 0);
            }
        }
    }

#pragma unroll
    for (int m = 0; m < 2; ++m)
#pragma unroll
        for (int n = 0; n < 2; ++n) red[w][m][n][lane] = acc[m][n];
    __syncthreads();

    {
        int mw = w >> 1, nw = w & 1;
        f32x4 sum = red[0][mw][nw][lane] + red[1][mw][nw][lane]
                  + red[2][mw][nw][lane] + red[3][mw][nw][lane];

        int col = c0 + nw * 16 + l15;
        float bv[4];
#pragma unroll
        for (int s = 0; s < 4; ++s) bv[s] = b[s * 256 + col];

#pragma unroll
        for (int r = 0; r < 4; ++r) {
            int grow = g0 + mw * 16 + l4 * 4 + r;
            if (grow < N_STRUCT) {
                float4 c4 = *(const float4*)(cnt + (size_t)grow * 4);
                out[(size_t)grow * 256 + col] =
                    sum[r] + c4.x * bv[0] + c4.y * bv[1]
                           + c4.z * bv[2] + c4.w * bv[3];
            }
        }
    }
}

extern "C" void kernel_launch(void* const* d_in, const int* in_sizes, int n_in,
                              void* d_out, int out_size, void* d_ws, size_t ws_size,
                              hipStream_t stream) {
    const float* x    = (const float*)d_in[0];
    const float* W    = (const float*)d_in[1];
    const float* b    = (const float*)d_in[2];
    const int* spec   = (const int*)d_in[3];
    const int* sidx   = (const int*)d_in[4];
    float* out        = (float*)d_out;

    char* ws = (char*)d_ws;
    unsigned short* Wt = (unsigned short*)ws;               // 524288 B
    unsigned short* S  = (unsigned short*)(ws + 524288);    // 4194304 B
    float* cnt  = (float*)(ws + 4718592);                   // 32768 B

    k_fused<<<WT_BLOCKS + (N_STRUCT + 3) / 4, 256, 0, stream>>>(x, W, spec, sidx, Wt, S, cnt);
    k_gemm5<<<(M_PAD / 32) * (D_OUT / 32), 256, 0, stream>>>(S, cnt, b, Wt, out);
}

// Round 11
// 50.603 us; speedup vs baseline: 27.8677x; 1.0750x over previous
//
#include <hip/hip_runtime.h>
#include <hip/hip_bf16.h>

#define N_ATOMS   200000
#define D_IN      256
#define D_OUT     256
#define N_SPECIES 4
#define N_STRUCT  2000
#define M_PAD     2048
#define KFLAT     1024
#define SEG_D     8          // ring slots per wave (was 16) -> 32 KB/block, 5 blocks/CU
#define SEG_AHEAD 7          // pipeline depth = SEG_D - 1
#define WT_BLOCKS 512

typedef __attribute__((ext_vector_type(8))) short bf16x8;
typedef __attribute__((ext_vector_type(4))) float f32x4;

typedef const __attribute__((address_space(1))) float gfloat;
typedef __attribute__((address_space(3))) float lfloat;

__device__ inline unsigned short f2bf(float f) {
    unsigned int u = __float_as_uint(f);
    unsigned int r = (u + 0x7fffu + ((u >> 16) & 1u)) >> 16;   // RNE
    return (unsigned short)r;
}

// ---- ws layout (bytes) ----
// 0        : Wt  bf16 [16][256][64]   = 524288   (kbg = s*4 + (k>>6), [n][k'] per block)
// 524288   : S   bf16 [2048][1024]    = 4194304  (rows >= 2000 stay poison, never stored)
// 4718592  : cnt f32  [2048][4]       = 32768

// 64-ary lower_bound over sorted sidx (whole wave participates)
__device__ __forceinline__ int lb64(const int* __restrict__ sidx, int key, int lane) {
    int lo = 0, hi = N_ATOMS;
    while (hi - lo > 64) {
        int step = (hi - lo + 63) >> 6;
        int pos  = lo + lane * step;
        int v    = (pos < hi) ? sidx[pos] : 0x7fffffff;
        unsigned long long m = __ballot(v < key);
        int c = __popcll(m);
        int nlo = (c == 0)  ? lo : (lo + (c - 1) * step + 1);
        int nhi = (c == 64) ? hi : min(hi, lo + c * step);
        lo = nlo; hi = nhi;
    }
    int pos = lo + lane;
    int v   = (pos < hi) ? sidx[pos] : 0x7fffffff;
    unsigned long long m = __ballot(v < key);
    return lo + __popcll(m);
}

// K1 (fused): blocks [0,512) = write-coalesced W transpose; rest = seg.
// Seg: one wave = one structure, depth-7 global_load_lds ring (32 KB LDS ->
// 5 blocks/CU = 20 waves/CU), counted vmcnt(6); spec masks pre-balloted into
// SGPRs so the hot loop's vmem queue holds ONLY ring loads.
__global__ __launch_bounds__(256) void k_fused(
        const float* __restrict__ x, const float* __restrict__ W,
        const int* __restrict__ spec, const int* __restrict__ sidx,
        unsigned short* __restrict__ Wt, unsigned short* __restrict__ S,
        float* __restrict__ cnt) {

    __shared__ __align__(16) float ring[4][SEG_D][256];   // 32 KB

    int t = threadIdx.x;
    int bid = blockIdx.x;

    if (bid < WT_BLOCKS) {
        int gid = bid * 256 + t;
        int o   = gid * 4;
        int kbg = o >> 14;
        int nn  = (o >> 6) & 255;
        int kp  = o & 63;
        int s   = kbg >> 2, kb = kbg & 3;
        int k0  = kb * 64 + kp;
        const float* wb = W + (size_t)s * 65536 + (size_t)k0 * 256 + nn;
        ushort4 u;
        u.x = f2bf(wb[0]);
        u.y = f2bf(wb[256]);
        u.z = f2bf(wb[512]);
        u.w = f2bf(wb[768]);
        *(ushort4*)(Wt + o) = u;
        return;
    }

    int w = t >> 6, lane = t & 63;
    int g = (bid - WT_BLOCKS) * 4 + w;
    if (g >= N_STRUCT) return;

    int s0 = lb64(sidx, g,     lane);
    int s1 = lb64(sidx, g + 1, lane);
    int n  = s1 - s0;

    f32x4 a0 = (f32x4){0.f,0.f,0.f,0.f}, a1 = a0, a2 = a0, a3 = a0;
    float c0 = 0.f, c1 = 0.f, c2 = 0.f, c3 = 0.f;

    if (n > 0) {
        int nm1 = n - 1;
        const float* gp0 = x + (size_t)s0 * 256 + lane * 4;

        unsigned long long m0[4], m1[4];
        bool fits = (n <= 256);
        if (fits) {
#pragma unroll
            for (int c = 0; c < 4; ++c) {
                int sv = spec[s0 + min(c * 64 + lane, nm1)];
                m0[c] = __ballot((sv & 1) != 0);
                m1[c] = __ballot((sv & 2) != 0);
            }
        }

        // drain lb64 + spec vector loads so vmcnt counts only ring loads
        asm volatile("s_waitcnt vmcnt(0)" ::: "memory");

#pragma unroll
        for (int j = 0; j < SEG_AHEAD; ++j) {
            int rr = min(j, nm1);
            __builtin_amdgcn_global_load_lds(
                (gfloat*)(gp0 + (size_t)rr * 256),
                (lfloat*)&ring[w][j][0], 16, 0, 0);
        }

#define CONS4(vv, sp)                                                     \
        switch (sp) {                                                     \
            case 0: a0 += vv; c0 += 1.f; break;                           \
            case 1: a1 += vv; c1 += 1.f; break;                           \
            case 2: a2 += vv; c2 += 1.f; break;                           \
            default: a3 += vv; c3 += 1.f; break; }

        if (fits) {
#pragma unroll
            for (int c = 0; c < 4; ++c) {
                int cb = c * 64;
                if (cb < n) {
                    unsigned long long mm0 = m0[c], mm1 = m1[c];
                    int ce = min(n, cb + 64);
                    for (int j = cb; j < ce; ++j) {
                        asm volatile("s_waitcnt vmcnt(6)" ::: "memory");
                        f32x4 v = *(const f32x4*)&ring[w][j & (SEG_D - 1)][lane * 4];
                        int r  = j - cb;
                        int sp = (int)((mm0 >> r) & 1ull) | ((int)((mm1 >> r) & 1ull) << 1);
                        CONS4(v, sp);
                        int rr = min(j + SEG_AHEAD, nm1);
                        __builtin_amdgcn_global_load_lds(
                            (gfloat*)(gp0 + (size_t)rr * 256),
                            (lfloat*)&ring[w][(j + SEG_AHEAD) & (SEG_D - 1)][0], 16, 0, 0);
                    }
                }
            }
        } else {
            for (int cb = 0; cb < n; cb += 64) {
                int spv = spec[s0 + min(cb + lane, nm1)];
                asm volatile("s_waitcnt vmcnt(0)" ::: "memory");
                unsigned long long mm0 = __ballot((spv & 1) != 0);
                unsigned long long mm1 = __ballot((spv & 2) != 0);
                int ce = min(n, cb + 64);
                for (int j = cb; j < ce; ++j) {
                    f32x4 v = *(const f32x4*)&ring[w][j & (SEG_D - 1)][lane * 4];
                    int r  = j - cb;
                    int sp = (int)((mm0 >> r) & 1ull) | ((int)((mm1 >> r) & 1ull) << 1);
                    CONS4(v, sp);
                    int rr = min(j + SEG_AHEAD, nm1);
                    __builtin_amdgcn_global_load_lds(
                        (gfloat*)(gp0 + (size_t)rr * 256),
                        (lfloat*)&ring[w][(j + SEG_AHEAD) & (SEG_D - 1)][0], 16, 0, 0);
                    asm volatile("s_waitcnt vmcnt(6)" ::: "memory");
                }
            }
        }
#undef CONS4
    }

    unsigned short* Sg = S + (size_t)g * KFLAT + lane * 4;
    ushort4 u;
    u.x = f2bf(a0[0]); u.y = f2bf(a0[1]); u.z = f2bf(a0[2]); u.w = f2bf(a0[3]);
    *(ushort4*)(Sg + 0)   = u;
    u.x = f2bf(a1[0]); u.y = f2bf(a1[1]); u.z = f2bf(a1[2]); u.w = f2bf(a1[3]);
    *(ushort4*)(Sg + 256) = u;
    u.x = f2bf(a2[0]); u.y = f2bf(a2[1]); u.z = f2bf(a2[2]); u.w = f2bf(a2[3]);
    *(ushort4*)(Sg + 512) = u;
    u.x = f2bf(a3[0]); u.y = f2bf(a3[1]); u.z = f2bf(a3[2]); u.w = f2bf(a3[3]);
    *(ushort4*)(Sg + 768) = u;

    if (lane == 0) {
        float4 c4; c4.x = c0; c4.y = c1; c4.z = c2; c4.w = c3;
        *(float4*)(cnt + (size_t)g * 4) = c4;
    }
}

// K2: K-split GEMM, 32 rows x 32 cols per block (512 blocks). Wave w computes
// species-w K-slice; all 4 waves participate in the LDS reduce.
__global__ __launch_bounds__(256) void k_gemm5(
        const unsigned short* __restrict__ S, const float* __restrict__ cnt,
        const float* __restrict__ b, const unsigned short* __restrict__ Wt,
        float* __restrict__ out) {

    __shared__ __align__(16) f32x4 red[4][2][2][64];   // [w][m][n][lane] = 16 KB

    int t = threadIdx.x, w = t >> 6, lane = t & 63;
    int l15 = lane & 15, l4 = lane >> 4;
    int bid = blockIdx.x;
    int g0 = (bid >> 3) * 32;        // 64 row-groups
    int c0 = (bid & 7) * 32;         // 8 col-blocks

    f32x4 acc[2][2];
#pragma unroll
    for (int m = 0; m < 2; ++m)
#pragma unroll
        for (int n = 0; n < 2; ++n) acc[m][n] = (f32x4){0.f, 0.f, 0.f, 0.f};

    const unsigned short* arow = S + (size_t)(g0 + l15) * KFLAT + w * 256 + l4 * 8;
    const unsigned short* wsp  = Wt + (size_t)w * 4 * 16384 + l4 * 8;

#pragma unroll
    for (int kb = 0; kb < 4; ++kb) {
#pragma unroll
        for (int ks = 0; ks < 2; ++ks) {
            bf16x8 af[2];
#pragma unroll
            for (int m = 0; m < 2; ++m)
                af[m] = *(const bf16x8*)(arow + (size_t)m * 16 * KFLAT + kb * 64 + ks * 32);
#pragma unroll
            for (int n = 0; n < 2; ++n) {
                bf16x8 bfr = *(const bf16x8*)(wsp + (size_t)kb * 16384
                                + (size_t)(c0 + n * 16 + l15) * 64 + ks * 32);
#pragma unroll
                for (int m = 0; m < 2; ++m)
                    acc[m][n] = __builtin_amdgcn_mfma_f32_16x16x32_bf16(af[m], bfr, acc[m][n], 0, 0, 0);
            }
        }
    }

#pragma unroll
    for (int m = 0; m < 2; ++m)
#pragma unroll
        for (int n = 0; n < 2; ++n) red[w][m][n][lane] = acc[m][n];
    __syncthreads();

    {
        int mw = w >> 1, nw = w & 1;
        f32x4 sum = red[0][mw][nw][lane] + red[1][mw][nw][lane]
                  + red[2][mw][nw][lane] + red[3][mw][nw][lane];

        int col = c0 + nw * 16 + l15;
        float bv[4];
#pragma unroll
        for (int s = 0; s < 4; ++s) bv[s] = b[s * 256 + col];

#pragma unroll
        for (int r = 0; r < 4; ++r) {
            int grow = g0 + mw * 16 + l4 * 4 + r;
            if (grow < N_STRUCT) {
                float4 c4 = *(const float4*)(cnt + (size_t)grow * 4);
                out[(size_t)grow * 256 + col] =
                    sum[r] + c4.x * bv[0] + c4.y * bv[1]
                           + c4.z * bv[2] + c4.w * bv[3];
            }
        }
    }
}

extern "C" void kernel_launch(void* const* d_in, const int* in_sizes, int n_in,
                              void* d_out, int out_size, void* d_ws, size_t ws_size,
                              hipStream_t stream) {
    const float* x    = (const float*)d_in[0];
    const float* W    = (const float*)d_in[1];
    const float* b    = (const float*)d_in[2];
    const int* spec   = (const int*)d_in[3];
    const int* sidx   = (const int*)d_in[4];
    float* out        = (float*)d_out;

    char* ws = (char*)d_ws;
    unsigned short* Wt = (unsigned short*)ws;               // 524288 B
    unsigned short* S  = (unsigned short*)(ws + 524288);    // 4194304 B
    float* cnt  = (float*)(ws + 4718592);                   // 32768 B

    k_fused<<<WT_BLOCKS + (N_STRUCT + 3) / 4, 256, 0, stream>>>(x, W, spec, sidx, Wt, S, cnt);
    k_gemm5<<<(M_PAD / 32) * (D_OUT / 32), 256, 0, stream>>>(S, cnt, b, Wt, out);
}